// Round 10
// baseline (4776.881 us; speedup 1.0000x reference)
//
#include <hip/hip_runtime.h>
#include <hip/hip_bf16.h>

typedef __attribute__((ext_vector_type(8))) short bf16x8;
typedef __attribute__((ext_vector_type(4))) float f32x4;

constexpr int NB = 64, NS = 512, ND = 512, NH = 1024;
constexpr int G4H = 4096;
constexpr int NWG = 256, NTHR = 512;
constexpr int PS  = 20;            // part[] row stride (floats)
constexpr int TRB = 3072;          // tile row stride bytes (512*2 + 1024*2)

__device__ inline unsigned short f2bf(float f) {
  union { float f; unsigned u; } v; v.f = f;
  unsigned r = v.u + 0x7FFFu + ((v.u >> 16) & 1u);  // RNE
  return (unsigned short)(r >> 16);
}
__device__ inline float sigmoidf_fast(float x) { return 1.0f / (1.0f + __expf(-x)); }
__device__ inline float tanhf_fast(float x) {
  float e = __expf(2.0f * x);
  return 1.0f - 2.0f / (e + 1.0f);
}
// XOR-swizzle intra-row byte offset (involution, applied on write AND read)
__device__ inline int swz(int row, int off) { return row * TRB + (off ^ ((row & 7) << 4)); }

// ---------------- prep: x -> bf16, zero exchange buffers ----------------
// exch: 2 ping-pong x 4 bb x 16 rows x 512 atoms (u64 = {2 bf16 | u32 ctr}) = 512KB
__global__ void prep_kernel(const float* __restrict__ x,
                            unsigned short* __restrict__ xbf,
                            unsigned long long* __restrict__ exch) {
  const int idx = blockIdx.x * blockDim.x + threadIdx.x;
  const int nthr = gridDim.x * blockDim.x;
  for (int i = idx; i < 2 * 4 * 16 * 512; i += nthr) exch[i] = 0ull;
  const float4* x4 = (const float4*)x;
  ushort4* xo = (ushort4*)xbf;
  const int n4 = NB * NS * ND / 4;
  for (int i = idx; i < n4; i += nthr) {
    float4 v = x4[i];
    ushort4 o;
    o.x = f2bf(v.x); o.y = f2bf(v.y); o.z = f2bf(v.z); o.w = f2bf(v.w);
    xo[i] = o;
  }
}

// ---------------- main persistent kernel ----------------
// h-exchange via self-validating 8B atoms {2 bf16, step ctr}: single LLC hop,
// no flags, no producer drain, no poll wave.
__global__ __launch_bounds__(NTHR, 2)
void lstm_kernel(const float* __restrict__ Wih,
                 const float* __restrict__ Whh,
                 const float* __restrict__ bias,
                 const unsigned short* __restrict__ xbf,
                 unsigned long long* __restrict__ exch,
                 float* __restrict__ out)
{
  const int tid  = threadIdx.x;
  const int wg   = blockIdx.x;
  const int wave = tid >> 6;
  const int lane = tid & 63;
  const int bb   = wg >> 6;       // batch block (hb-major: XCD-chunk locality)
  const int hb   = wg & 63;       // hidden block (16 cols)
  const int gp   = wave & 1;      // gate pair: 0 -> {i,f}, 1 -> {g,o}
  const int q    = wave >> 1;     // K quarter (x-ksteps 4q..4q+3, h-ksteps 8q..8q+7)

  __shared__ unsigned short tile[16 * 1536];  // [16][512 x | 1024 h] bf16, swizzled
  __shared__ float part[16][16 * PS];
  __shared__ float c_state[256];

  if (tid < 256) c_state[tid] = 0.0f;

  // ---------- one-time weight B-frag gather (col = lane&15, k = kbase+(lane>>4)*8+j) ----
  const int kg0  = (lane >> 4) << 3;
  const int colb = (hb << 4) + (lane & 15);
  bf16x8 wx[2][4], wh[2][8];
#pragma unroll
  for (int gg = 0; gg < 2; ++gg) {
    const int col = ((gp * 2 + gg) << 10) + colb;
#pragma unroll
    for (int s = 0; s < 4; ++s) {
      const int k0 = (q * 4 + s) * 32 + kg0;
#pragma unroll
      for (int j = 0; j < 8; ++j)
        wx[gg][s][j] = (short)f2bf(Wih[(size_t)(k0 + j) * G4H + col]);
    }
#pragma unroll
    for (int u = 0; u < 8; ++u) {
      const int k0 = (q * 8 + u) * 32 + kg0;
#pragma unroll
      for (int j = 0; j < 8; ++j)
        wh[gg][u][j] = (short)f2bf(Whh[(size_t)(k0 + j) * G4H + col]);
    }
  }

  // ---------- prologue: stage x(0); zero h region ----------
  for (int c = tid; c < 1024; c += NTHR) {
    const int row = c >> 6, sl = c & 63;
    const unsigned short* src = xbf + (size_t)(bb * 16 + row) * (NS * ND) + sl * 8;
    *(uint4*)((char*)tile + swz(row, sl * 16)) = *(const uint4*)src;
  }
  for (int c = tid; c < 2048; c += NTHR) {
    const int row = c >> 7, sl = c & 127;
    *(uint4*)((char*)tile + swz(row, 1024 + sl * 16)) = uint4{0, 0, 0, 0};
  }
  __syncthreads();

  const int arow = lane & 15;
  float* ht_out = out + (size_t)NB * NS * NH;
  float* ct_out = ht_out + NB * NH;

  // consumer atom mapping: row = tid>>5, atoms c2 in [ (tid&31)*16, +16 )
  const int crow = tid >> 5;
  const int cc2  = (tid & 31) << 4;

  for (int t = 0; t < NS; ++t) {
    const unsigned long long* abase =
        exch + ((size_t)((t & 1) * 4 + bb) * 16 + crow) * 512 + cc2;

    // ---- P1: issue 16 atom loads (self-validating h(t-1)) ----
    unsigned long long atm[16];
    if (t > 0) {
#pragma unroll
      for (int i = 0; i < 16; ++i)
        atm[i] = __hip_atomic_load(abase + i, __ATOMIC_RELAXED, __HIP_MEMORY_SCOPE_AGENT);
    }

    // ---- P2: x-part MFMAs (hide atom-load latency) ----
    f32x4 a0 = {0.f, 0.f, 0.f, 0.f}, a1 = {0.f, 0.f, 0.f, 0.f};
#pragma unroll
    for (int s = 0; s < 4; ++s) {
      const int off = ((q * 4 + s) * 32 + kg0) * 2;
      bf16x8 af = *(const bf16x8*)((const char*)tile + swz(arow, off));
      a0 = __builtin_amdgcn_mfma_f32_16x16x32_bf16(af, wx[0][s], a0, 0, 0, 0);
      a1 = __builtin_amdgcn_mfma_f32_16x16x32_bf16(af, wx[1][s], a1, 0, 0, 0);
    }

    // ---- P3: validate (retry stale) + ds_write h slice ----
    if (t > 0) {
      const unsigned int tgt = (unsigned int)t;
      bool done = false;
      while (!done) {
        done = true;
#pragma unroll
        for (int i = 0; i < 16; ++i) {
          if ((unsigned int)(atm[i] >> 32) != tgt) {
            atm[i] = __hip_atomic_load(abase + i, __ATOMIC_RELAXED, __HIP_MEMORY_SCOPE_AGENT);
            done = false;
          }
        }
      }
#pragma unroll
      for (int u = 0; u < 4; ++u) {
        uint4 v;
        v.x = (unsigned int)atm[4 * u + 0];
        v.y = (unsigned int)atm[4 * u + 1];
        v.z = (unsigned int)atm[4 * u + 2];
        v.w = (unsigned int)atm[4 * u + 3];
        *(uint4*)((char*)tile + swz(crow, 1024 + (cc2 << 2) + (u << 4))) = v;
      }
    }
    __syncthreads();  // P4: h region ready

    // ---- P5: h-part MFMAs ----
#pragma unroll
    for (int u = 0; u < 8; ++u) {
      const int off = 1024 + ((q * 8 + u) * 32 + kg0) * 2;
      bf16x8 af = *(const bf16x8*)((const char*)tile + swz(arow, off));
      a0 = __builtin_amdgcn_mfma_f32_16x16x32_bf16(af, wh[0][u], a0, 0, 0, 0);
      a1 = __builtin_amdgcn_mfma_f32_16x16x32_bf16(af, wh[1][u], a1, 0, 0, 0);
    }

    // ---- P6: partial tiles (C/D: col = lane&15, row = (lane>>4)*4 + reg) ----
    {
      const int r0 = (lane >> 4) << 2;
      const int cc = lane & 15;
#pragma unroll
      for (int j = 0; j < 4; ++j) {
        part[wave * 2 + 0][(r0 + j) * PS + cc] = a0[j];
        part[wave * 2 + 1][(r0 + j) * PS + cc] = a1[j];
      }
    }
    __syncthreads();  // P6b

    // ---- P7: waves 0-3 epilogue + atom stores; waves 4-7 stage x(t+1) ----
    if (tid < 256) {
      const int ec = tid & 15;
      const int er = tid >> 4;
      float pre[4];
#pragma unroll
      for (int go = 0; go < 4; ++go) {
        float s = bias[(go << 10) + (hb << 4) + ec];
#pragma unroll
        for (int qq = 0; qq < 4; ++qq)
          s += part[(qq * 2 + (go >> 1)) * 2 + (go & 1)][er * PS + ec];
        pre[go] = s;
      }
      const float it = sigmoidf_fast(pre[0]);
      const float ft = sigmoidf_fast(pre[1]);
      const float gt = tanhf_fast(pre[2]);
      const float ot = sigmoidf_fast(pre[3]);
      const float cn = ft * c_state[tid] + it * gt;
      c_state[tid] = cn;
      const float hn = ot * tanhf_fast(cn);
      const int row  = (bb << 4) + er;
      const int hcol = (hb << 4) + ec;
      if (t < NS - 1) {
        // self-validating atom: {ctr=t+1 | bf16(h_odd) | bf16(h_even)}
        unsigned int my = (unsigned int)f2bf(hn);
        unsigned int pa = (unsigned int)__shfl_xor((int)my, 1, 64);
        if ((tid & 1) == 0) {
          unsigned long long av = ((unsigned long long)(unsigned int)(t + 1) << 32)
                                | (pa << 16) | my;
          unsigned long long* p = exch + ((size_t)(((t + 1) & 1) * 4 + bb) * 16 + er) * 512
                                       + hb * 8 + (ec >> 1);
          __hip_atomic_store(p, av, __ATOMIC_RELAXED, __HIP_MEMORY_SCOPE_AGENT);
        }
        __builtin_nontemporal_store(hn, &out[(size_t)row * (NS * NH) + (size_t)t * NH + hcol]);
      } else {
        out[(size_t)row * (NS * NH) + (size_t)t * NH + hcol] = hn;
        ht_out[row * NH + hcol] = hn;
        ct_out[row * NH + hcol] = cn;
      }
    } else if (t < NS - 1) {
      // 1024 x-chunks over 256 threads (4 each), hidden under the epilogue
      for (int c = tid - 256; c < 1024; c += 256) {
        const int row = c >> 6, sl = c & 63;
        const unsigned short* src = xbf + (size_t)(bb * 16 + row) * (NS * ND)
                                        + (size_t)(t + 1) * ND + sl * 8;
        *(uint4*)((char*)tile + swz(row, sl * 16)) = *(const uint4*)src;
      }
    }
    if (t < NS - 1) __syncthreads();  // P10: release into step t+1
  }
}

extern "C" void kernel_launch(void* const* d_in, const int* in_sizes, int n_in,
                              void* d_out, int out_size, void* d_ws, size_t ws_size,
                              hipStream_t stream) {
  const float* x    = (const float*)d_in[0];
  const float* wih  = (const float*)d_in[1];
  const float* whh  = (const float*)d_in[2];
  const float* bias = (const float*)d_in[3];
  float* out = (float*)d_out;

  // ws layout: [exch 512KB][xbf NB*NS*ND bf16 = 32MB]
  unsigned long long* exch = (unsigned long long*)d_ws;
  unsigned short*     xbf  = (unsigned short*)((char*)d_ws + 524288);

  prep_kernel<<<1024, 256, 0, stream>>>(x, xbf, exch);

  void* args[] = { (void*)&wih, (void*)&whh, (void*)&bias,
                   (void*)&xbf, (void*)&exch, (void*)&out };
  hipLaunchCooperativeKernel((const void*)lstm_kernel, dim3(NWG), dim3(NTHR),
                             args, 0, stream);
}

// Round 11
// 2042.820 us; speedup vs baseline: 2.3384x; 2.3384x over previous
//
#include <hip/hip_runtime.h>
#include <hip/hip_bf16.h>

typedef __attribute__((ext_vector_type(8))) short bf16x8;
typedef __attribute__((ext_vector_type(4))) float f32x4;

constexpr int NB = 64, NS = 512, ND = 512, NH = 1024;
constexpr int G4H = 4096;
constexpr int NWG = 256, NTHR = 512;
constexpr int PS  = 20;            // part[] row stride (floats)
constexpr int TRB = 3072;          // tile row stride bytes (512*2 + 1024*2)

__device__ inline unsigned short f2bf(float f) {
  union { float f; unsigned u; } v; v.f = f;
  unsigned r = v.u + 0x7FFFu + ((v.u >> 16) & 1u);  // RNE
  return (unsigned short)(r >> 16);
}
__device__ inline unsigned int pk2(float lo, float hi) {
  return (unsigned int)f2bf(lo) | ((unsigned int)f2bf(hi) << 16);
}
__device__ inline float sigmoidf_fast(float x) { return 1.0f / (1.0f + __expf(-x)); }
__device__ inline float tanhf_fast(float x) {
  float e = __expf(2.0f * x);
  return 1.0f - 2.0f / (e + 1.0f);
}
// XOR-swizzle intra-row byte offset (involution, applied on write AND read)
__device__ inline int swz(int row, int off) { return row * TRB + (off ^ ((row & 7) << 4)); }

// ---------------- prep: x -> bf16, zero flags ----------------
__global__ void prep_kernel(const float* __restrict__ x,
                            unsigned short* __restrict__ xbf,
                            unsigned int* __restrict__ flags) {
  const int idx = blockIdx.x * blockDim.x + threadIdx.x;
  const int nthr = gridDim.x * blockDim.x;
  for (int i = idx; i < NWG * 16; i += nthr) flags[i] = 0u;
  const float4* x4 = (const float4*)x;
  ushort4* xo = (ushort4*)xbf;
  const int n4 = NB * NS * ND / 4;
  for (int i = idx; i < n4; i += nthr) {
    float4 v = x4[i];
    ushort4 o;
    o.x = f2bf(v.x); o.y = f2bf(v.y); o.z = f2bf(v.z); o.w = f2bf(v.w);
    xo[i] = o;
  }
}

// ---------------- main persistent kernel (r7 structure) ----------------
// h-exchange = out itself (fp32 h-history, write-once per address per launch):
// producers sc1-store {2 fp32} u64 atoms (LLC-direct); consumers read via the
// NORMAL cached path (L2/L1) — safe because no address is ever rewritten within
// a launch, and the flag orders LLC data ahead of any L2 fill.
__global__ __launch_bounds__(NTHR)
void lstm_kernel(const float* __restrict__ Wih,
                 const float* __restrict__ Whh,
                 const float* __restrict__ bias,
                 const unsigned short* __restrict__ xbf,
                 unsigned int* __restrict__ flags,
                 float* __restrict__ out)
{
  const int tid  = threadIdx.x;
  const int wg   = blockIdx.x;
  const int wave = tid >> 6;
  const int lane = tid & 63;
  const int bb   = wg >> 6;       // batch block (hb-major: one bb per XCD chunk)
  const int hb   = wg & 63;       // hidden block (16 cols)
  const int gp   = wave & 1;      // gate pair: 0 -> {i,f}, 1 -> {g,o}
  const int q    = wave >> 1;     // K quarter (x-ksteps 4q..4q+3, h-ksteps 8q..8q+7)

  __shared__ unsigned short tile[16 * 1536];  // [16][512 x | 1024 h] bf16, swizzled
  __shared__ float part[16][16 * PS];
  __shared__ float c_state[256];

  if (tid < 256) c_state[tid] = 0.0f;

  // ---------- one-time weight B-frag gather (col = lane&15, k = kbase+(lane>>4)*8+j) ----
  const int kg0  = (lane >> 4) << 3;
  const int colb = (hb << 4) + (lane & 15);
  bf16x8 wx[2][4], wh[2][8];
#pragma unroll
  for (int gg = 0; gg < 2; ++gg) {
    const int col = ((gp * 2 + gg) << 10) + colb;
#pragma unroll
    for (int s = 0; s < 4; ++s) {
      const int k0 = (q * 4 + s) * 32 + kg0;
#pragma unroll
      for (int j = 0; j < 8; ++j)
        wx[gg][s][j] = (short)f2bf(Wih[(size_t)(k0 + j) * G4H + col]);
    }
#pragma unroll
    for (int u = 0; u < 8; ++u) {
      const int k0 = (q * 8 + u) * 32 + kg0;
#pragma unroll
      for (int j = 0; j < 8; ++j)
        wh[gg][u][j] = (short)f2bf(Whh[(size_t)(k0 + j) * G4H + col]);
    }
  }

  // ---------- prologue: stage x(0); zero h region ----------
  for (int c = tid; c < 1024; c += NTHR) {       // 16 rows x 64 slots(16B) of x
    const int row = c >> 6, sl = c & 63;
    const unsigned short* src = xbf + (size_t)(bb * 16 + row) * (NS * ND) + sl * 8;
    *(uint4*)((char*)tile + swz(row, sl * 16)) = *(const uint4*)src;
  }
  for (int c = tid; c < 2048; c += NTHR) {       // 16 rows x 128 slots of h
    const int row = c >> 7, sl = c & 127;
    *(uint4*)((char*)tile + swz(row, 1024 + sl * 16)) = uint4{0, 0, 0, 0};
  }
  __syncthreads();

  const int arow = lane & 15;
  float* ht_out = out + (size_t)NB * NS * NH;
  float* ct_out = ht_out + NB * NH;

  for (int t = 0; t < NS; ++t) {
    // ---- P1: issue CACHED fp32 h(t-1) loads from out (L2-hit for 31/32 WGs) ----
    float4 hv[8];
    if (t > 0) {
#pragma unroll
      for (int u = 0; u < 4; ++u) {
        const int row = 2 * wave + (u >> 1);
        const int sl  = (u & 1) * 64 + lane;
        const float* p = out + (size_t)(bb * 16 + row) * (NS * NH)
                             + (size_t)(t - 1) * NH + sl * 8;
        hv[2 * u]     = *(const float4*)p;
        hv[2 * u + 1] = *(const float4*)(p + 4);
      }
    }

    // ---- P2: x-part MFMAs (every wave has 8 — hides h-load latency) ----
    f32x4 a0 = {0.f, 0.f, 0.f, 0.f}, a1 = {0.f, 0.f, 0.f, 0.f};
#pragma unroll
    for (int s = 0; s < 4; ++s) {
      const int off = ((q * 4 + s) * 32 + kg0) * 2;
      bf16x8 af = *(const bf16x8*)((const char*)tile + swz(arow, off));
      a0 = __builtin_amdgcn_mfma_f32_16x16x32_bf16(af, wx[0][s], a0, 0, 0, 0);
      a1 = __builtin_amdgcn_mfma_f32_16x16x32_bf16(af, wx[1][s], a1, 0, 0, 0);
    }

    // ---- P3: convert fp32->bf16 + ds_write h slice (lane-contiguous 16B) ----
    if (t > 0) {
#pragma unroll
      for (int u = 0; u < 4; ++u) {
        const int row = 2 * wave + (u >> 1);
        const int sl  = (u & 1) * 64 + lane;
        uint4 v;
        v.x = pk2(hv[2 * u].x,     hv[2 * u].y);
        v.y = pk2(hv[2 * u].z,     hv[2 * u].w);
        v.z = pk2(hv[2 * u + 1].x, hv[2 * u + 1].y);
        v.w = pk2(hv[2 * u + 1].z, hv[2 * u + 1].w);
        *(uint4*)((char*)tile + swz(row, 1024 + sl * 16)) = v;
      }
    }
    __syncthreads();  // P4: h region ready

    // ---- P5: h-part MFMAs ----
#pragma unroll
    for (int u = 0; u < 8; ++u) {
      const int off = 1024 + ((q * 8 + u) * 32 + kg0) * 2;
      bf16x8 af = *(const bf16x8*)((const char*)tile + swz(arow, off));
      a0 = __builtin_amdgcn_mfma_f32_16x16x32_bf16(af, wh[0][u], a0, 0, 0, 0);
      a1 = __builtin_amdgcn_mfma_f32_16x16x32_bf16(af, wh[1][u], a1, 0, 0, 0);
    }

    // ---- P6: partial tiles (C/D: col = lane&15, row = (lane>>4)*4 + reg) ----
    {
      const int r0 = (lane >> 4) << 2;
      const int cc = lane & 15;
#pragma unroll
      for (int j = 0; j < 4; ++j) {
        part[wave * 2 + 0][(r0 + j) * PS + cc] = a0[j];
        part[wave * 2 + 1][(r0 + j) * PS + cc] = a1[j];
      }
    }
    __syncthreads();  // P6b

    // ---- P7: epilogue (256 threads); single sc1 u64 store = output + exchange ----
    if (tid < 256) {
      const int ec = tid & 15;
      const int er = tid >> 4;
      float pre[4];
#pragma unroll
      for (int go = 0; go < 4; ++go) {
        float s = bias[(go << 10) + (hb << 4) + ec];
#pragma unroll
        for (int qq = 0; qq < 4; ++qq)
          s += part[(qq * 2 + (go >> 1)) * 2 + (go & 1)][er * PS + ec];
        pre[go] = s;
      }
      const float it = sigmoidf_fast(pre[0]);
      const float ft = sigmoidf_fast(pre[1]);
      const float gt = tanhf_fast(pre[2]);
      const float ot = sigmoidf_fast(pre[3]);
      const float cn = ft * c_state[tid] + it * gt;
      c_state[tid] = cn;
      const float hn = ot * tanhf_fast(cn);
      const int row  = (bb << 4) + er;
      const int hcol = (hb << 4) + ec;
      const size_t ooff = (size_t)row * (NS * NH) + (size_t)t * NH + hcol;
      if (t == NS - 1) {
        out[ooff] = hn;
        ht_out[row * NH + hcol] = hn;
        ct_out[row * NH + hcol] = cn;
      } else {
        unsigned int my = __float_as_uint(hn);
        unsigned int pa = (unsigned int)__shfl_xor((int)my, 1, 64);
        if ((tid & 1) == 0) {
          unsigned long long pv = (unsigned long long)my | ((unsigned long long)pa << 32);
          __hip_atomic_store((unsigned long long*)(out + ooff), pv,
                             __ATOMIC_RELAXED, __HIP_MEMORY_SCOPE_AGENT);
        }
      }
    }

    if (t < NS - 1) {
      // P8: drain waves 0-3's sc1 stores, then make them WG-visible
      if (wave < 4) asm volatile("s_waitcnt vmcnt(0)" ::: "memory");
      __syncthreads();

      // P9: flag + poll on wave 7; x(t+1) staging on waves 0-6
      if (tid == (7 << 6))
        __hip_atomic_store(flags + (size_t)wg * 16, (unsigned int)(t + 1),
                           __ATOMIC_RELAXED, __HIP_MEMORY_SCOPE_AGENT);
      if (wave == 7) {
        const unsigned int target = (unsigned int)(t + 1);
        const unsigned int* fp = flags + (size_t)((bb << 6) | lane) * 16;
        while (true) {
          unsigned int fv = __hip_atomic_load(fp, __ATOMIC_RELAXED, __HIP_MEMORY_SCOPE_AGENT);
          if (__all((int)(fv >= target))) break;
          __builtin_amdgcn_s_sleep(1);
        }
      } else {
        for (int c = tid; c < 1024; c += 448) {
          const int row = c >> 6, sl = c & 63;
          const unsigned short* src = xbf + (size_t)(bb * 16 + row) * (NS * ND)
                                          + (size_t)(t + 1) * ND + sl * 8;
          *(uint4*)((char*)tile + swz(row, sl * 16)) = *(const uint4*)src;
        }
      }
      __syncthreads();  // P10: release into step t+1
    }
  }
}

extern "C" void kernel_launch(void* const* d_in, const int* in_sizes, int n_in,
                              void* d_out, int out_size, void* d_ws, size_t ws_size,
                              hipStream_t stream) {
  const float* x    = (const float*)d_in[0];
  const float* wih  = (const float*)d_in[1];
  const float* whh  = (const float*)d_in[2];
  const float* bias = (const float*)d_in[3];
  float* out = (float*)d_out;

  // ws layout: [flags 16KB][xbf NB*NS*ND bf16 = 32MB]
  unsigned int*   flags = (unsigned int*)d_ws;
  unsigned short* xbf   = (unsigned short*)((char*)d_ws + 16384);

  prep_kernel<<<1024, 256, 0, stream>>>(x, xbf, flags);

  void* args[] = { (void*)&wih, (void*)&whh, (void*)&bias,
                   (void*)&xbf, (void*)&flags, (void*)&out };
  hipLaunchCooperativeKernel((const void*)lstm_kernel, dim3(NWG), dim3(NTHR),
                             args, 0, stream);
}